// Round 9
// baseline (159.774 us; speedup 1.0000x reference)
//
#include <hip/hip_runtime.h>
#include <math.h>

#define Bq 4
#define Cq 64
#define Hq 160
#define Wq 160
#define HWq (Hq*Wq)      // 25600
#define OUTq 64
#define KKq 576          // Cq*9
#define KS  18           // KKq/32
#define SROW 584         // padded kk row (fp16 units); 1168 B, rows 16B-aligned

typedef __attribute__((ext_vector_type(8))) _Float16 half8;
typedef __attribute__((ext_vector_type(2))) _Float16 half2v;
typedef __attribute__((ext_vector_type(4))) float float4v;
typedef unsigned short ushort_t;
typedef unsigned int uint_t;

__device__ __forceinline__ ushort_t f2h(float f) {          // RNE f32->f16
    return __builtin_bit_cast(ushort_t, (_Float16)f);
}
__device__ __forceinline__ uint_t f2hdup(float f) {         // (h,h) packed
    uint_t u = (uint_t)f2h(f);
    return u | (u << 16);
}
__device__ __forceinline__ half2v h2(uint_t u) {
    return __builtin_bit_cast(half2v, u);
}
#define MFMA16(a,b,c) __builtin_amdgcn_mfma_f32_16x16x32_f16((a),(b),(c),0,0,0)

// ---------------------------------------------------------------------------
// K_prep: x NCHW f32 -> xt NHWC fp16; weight prepack on first 216 blocks.
// ---------------------------------------------------------------------------
__global__ void __launch_bounds__(256) k_prep(const float* __restrict__ x,
                                              const float* __restrict__ dcn_w,
                                              const float* __restrict__ off_w,
                                              const float* __restrict__ msk_w,
                                              ushort_t* __restrict__ xt,
                                              ushort_t* __restrict__ wtf,
                                              ushort_t* __restrict__ cwf2) {
    __shared__ float tile[64][65];
    int b = blockIdx.y, hw0 = blockIdx.x * 64;
    int tid = threadIdx.x;
    int l16 = tid & 15, crow = tid >> 4;        // crow 0..15
#pragma unroll
    for (int i = 0; i < 4; ++i) {
        int c = crow + i*16;
        float4 v = *(const float4*)(x + ((size_t)(b*Cq + c))*HWq + hw0 + l16*4);
        tile[c][l16*4+0] = v.x;
        tile[c][l16*4+1] = v.y;
        tile[c][l16*4+2] = v.z;
        tile[c][l16*4+3] = v.w;
    }
    __syncthreads();
#pragma unroll
    for (int it = 0; it < 4; ++it) {
        int hw = (tid >> 4) + it*16;
        int c4 = (tid & 15) * 4;
        uint_t v0 = (uint_t)f2h(tile[c4+0][hw]) | ((uint_t)f2h(tile[c4+1][hw]) << 16);
        uint_t v1 = (uint_t)f2h(tile[c4+2][hw]) | ((uint_t)f2h(tile[c4+3][hw]) << 16);
        uint2 vv; vv.x = v0; vv.y = v1;
        *(uint2*)(xt + ((size_t)b*HWq + hw0 + hw)*64 + c4) = vv;
    }
    if (blockIdx.y == 0 && blockIdx.x < 216) {
        int id = blockIdx.x*256 + tid;
        if (id < 4*KS*512) {
            int j = id & 7, ln = (id>>3) & 63, ks = (id>>9) % KS, g = id/(512*KS);
            int kk = ks*32 + (ln>>4)*8 + j;
            int c  = kk & 63, kt = kk >> 6;
            int m  = g*16 + (ln&15);
            wtf[id] = f2h(dcn_w[m*KKq + c*9 + kt]);
        }
        int id2 = id - 4*KS*512;
        if (id2 >= 0 && id2 < 9*2*2*512) {
            int j = id2 & 7, ln = (id2>>3) & 63;
            int ks2 = (id2>>9) & 1, g = (id2>>10) & 1, k = id2 >> 11;
            int co = g*16 + (ln&15);
            int c  = ks2*32 + (ln>>4)*8 + j;
            float w = 0.f;
            if (co < 18)      w = off_w[co*KKq + c*9 + k];
            else if (co < 27) w = msk_w[(co-18)*KKq + c*9 + k];
            cwf2[id2] = f2h(w);
        }
    }
}

// ---------------------------------------------------------------------------
// K_fused (r6 base, instruction-cut round):
//  - NO halo staging: conv B-frags load directly from xt (L2-hot via XCD
//    swizzle); compile-time (ky,kx,ks2) per unrolled step, clamp+zero-mask
//    reproduces halo zero-fill bit-exactly. One barrier removed.
//  - Phase B: QUARTER-wave per (p,tap), 4 ch/lane, dwordx2 gathers, 9 iters
//    (halves Phase-B instruction count vs half-wave/18); weights stay
//    pre-duplicated uint4 in LDS; 1-deep prefetch kept.
//  - XCD swizzle, conv a-frag hoist, pre-shifted byte-offset descs,
//    Phase C 1-deep a-prefetch all kept from r6/r8.
// LDS: union{s_part(4096) | s_s(18688)} + s_A(2304) + s_W(2304) = 23,296 B.
// ---------------------------------------------------------------------------
__global__ void __launch_bounds__(256, 6) k_fused(const ushort_t* __restrict__ xt,
                                                  const ushort_t* __restrict__ cwf2,
                                                  const float* __restrict__ off_b,
                                                  const float* __restrict__ msk_b,
                                                  const ushort_t* __restrict__ wtf,
                                                  float* __restrict__ out) {
    __shared__ __align__(16) char s_mem[16*SROW*2];          // 18,688 B
    __shared__ __align__(16) uint4 s_A[144];                 //  2,304 B
    __shared__ __align__(16) uint4 s_W[144];                 //  2,304 B
    float*    s_part = (float*)s_mem;                        // conv partials
    ushort_t* s_s    = (ushort_t*)s_mem;                     // Phase B/C

    // XCD-aware swizzle: contiguous 800-block chunk per XCD.
    int bid = blockIdx.x;                 // 6400 = 4 * 160 * 10
    int blk = (bid & 7) * 800 + (bid >> 3);
    int jt = blk % 10, i = (blk/10) % Hq, b = blk/(10*Hq);
    int j0 = jt*16;
    int tid = threadIdx.x, lane = tid & 63, grp = tid >> 6;
    int n = lane & 15, quad = lane >> 4;

    // ---- Conv A-fragments: hoisted loads ----
    int gM = grp & 1, kh = grp >> 1;
    half8 af[9];
#pragma unroll
    for (int s = 0; s < 9; ++s) {
        int st = kh*9 + s;                // 0..17
        int k = st >> 1, ks2 = st & 1;
        af[s] = *(const half8*)(cwf2 + (size_t)(((k*2+gM)*2+ks2)*512 + lane*8));
    }

    const ushort_t* xtb = xt + (size_t)b*HWq*64;

    // ---- Offset/mask conv: direct-global B-frags (no halo staging) ----
    {
        float4v cacc = {0.f,0.f,0.f,0.f};
#pragma unroll
        for (int s = 0; s < 9; ++s) {
            int st = kh*9 + s;            // 0..17
            int k = st >> 1, ks2 = st & 1;
            int ky = k/3, kx = k - (k/3)*3;
            int y  = i + ky - 1;                  // wave-uniform
            int xx = j0 + n + kx - 1;             // per-lane
            int yc = min(max(y, 0), Hq-1);
            int xc = min(max(xx, 0), Wq-1);
            uint4 raw = *(const uint4*)(xtb + ((size_t)yc*Wq + xc)*64 + quad*8 + ks2*32);
            uint_t msk = ((y >= 0) & (y < Hq) & (xx >= 0) & (xx < Wq)) ? 0xFFFFFFFFu : 0u;
            raw.x &= msk; raw.y &= msk; raw.z &= msk; raw.w &= msk;
            cacc = MFMA16(af[s], __builtin_bit_cast(half8, raw), cacc);
        }
        *(float4v*)(s_part + grp*256 + lane*4) = cacc;
    }
    __syncthreads();

    // ---- Phase A: tap descriptors from conv partials ----
    if (tid < 144) {
        int p = tid & 15, k = tid >> 4;
        #define RD(co) (s_part[(((co)>>4)*256)     + ((((co)&15)>>2)*16 + p)*4 + ((co)&3)] + \
                        s_part[(2 + ((co)>>4))*256 + ((((co)&15)>>2)*16 + p)*4 + ((co)&3)])
        float oy = RD(2*k)   + off_b[2*k];
        float ox = RD(2*k+1) + off_b[2*k+1];
        float mv = RD(18+k)  + msk_b[k];
        #undef RD
        float m = 1.f/(1.f + __expf(-mv));
        float py = oy + (float)(i - 1 + k/3);
        float px = ox + (float)(j0 + p - 1 + (k - (k/3)*3));
        float fy = floorf(py), fx = floorf(px);
        int y0 = (int)fy, x0 = (int)fx;
        float wy1 = py - fy, wx1 = px - fx;
        float wy0 = 1.f - wy1, wx0 = 1.f - wx1;
        bool vy0 = (y0 >= 0) & (y0 < Hq),   vy1 = (y0+1 >= 0) & (y0+1 < Hq);
        bool vx0 = (x0 >= 0) & (x0 < Wq),   vx1 = (x0+1 >= 0) & (x0+1 < Wq);
        int yc0 = min(max(y0,   0), Hq-1), yc1 = min(max(y0+1, 0), Hq-1);
        int xc0 = min(max(x0,   0), Wq-1), xc1 = min(max(x0+1, 0), Wq-1);
        s_A[tid] = make_uint4((uint_t)((yc0*Wq + xc0)*128),
                              (uint_t)((yc0*Wq + xc1)*128),
                              (uint_t)((yc1*Wq + xc0)*128),
                              (uint_t)((yc1*Wq + xc1)*128));
        s_W[tid] = make_uint4(f2hdup((vy0 && vx0) ? wy0*wx0*m : 0.f),
                              f2hdup((vy0 && vx1) ? wy0*wx1*m : 0.f),
                              f2hdup((vy1 && vx0) ? wy1*wx0*m : 0.f),
                              f2hdup((vy1 && vx1) ? wy1*wx1*m : 0.f));
    }
    __syncthreads();

    // ---- Phase B: quarter-wave per (p,tap), 4 ch/lane, 9 iters, 1-deep ----
    {
        int sub = lane >> 4;              // quarter 0..3
        int ch8 = (lane & 15) * 8;        // byte offset of 4-ch slice
        int q16 = grp*4 + sub;            // pixel p = q16 (0..15)
        const char* xtbB = (const char*)xtb;
        char* s_sb = (char*)s_s;
        uint_t dstb = (uint_t)(q16*(SROW*2) + ch8);
        // prefetch iter 0 (task t = 0*16 + q16)
        uint4 A  = s_A[q16];
        uint4 Wt = s_W[q16];
        uint2 u00 = *(const uint2*)(xtbB + A.x + ch8);
        uint2 u01 = *(const uint2*)(xtbB + A.y + ch8);
        uint2 u10 = *(const uint2*)(xtbB + A.z + ch8);
        uint2 u11 = *(const uint2*)(xtbB + A.w + ch8);
#pragma unroll
        for (int iter = 0; iter < 9; ++iter) {
            uint4 Wc = Wt;
            uint2 v00 = u00, v01 = u01, v10 = u10, v11 = u11;
            if (iter < 8) {               // prefetch iter+1 (task (iter+1)*16+q16)
                A  = s_A[(iter+1)*16 + q16];
                Wt = s_W[(iter+1)*16 + q16];
                u00 = *(const uint2*)(xtbB + A.x + ch8);
                u01 = *(const uint2*)(xtbB + A.y + ch8);
                u10 = *(const uint2*)(xtbB + A.z + ch8);
                u11 = *(const uint2*)(xtbB + A.w + ch8);
            }
            half2v lo = h2(v00.x) * h2(Wc.x);
            half2v hi = h2(v00.y) * h2(Wc.x);
            lo = __builtin_elementwise_fma(h2(v01.x), h2(Wc.y), lo);
            hi = __builtin_elementwise_fma(h2(v01.y), h2(Wc.y), hi);
            lo = __builtin_elementwise_fma(h2(v10.x), h2(Wc.z), lo);
            hi = __builtin_elementwise_fma(h2(v10.y), h2(Wc.z), hi);
            lo = __builtin_elementwise_fma(h2(v11.x), h2(Wc.w), lo);
            hi = __builtin_elementwise_fma(h2(v11.y), h2(Wc.w), hi);
            uint2 res;
            res.x = __builtin_bit_cast(uint_t, lo);
            res.y = __builtin_bit_cast(uint_t, hi);
            *(uint2*)(s_sb + dstb + iter*128) = res;   // row p, col-block k=iter
        }
    }
    __syncthreads();

    // ---- Phase C: wave grp -> o rows [grp*16, +16), 16 pixels ----
    float4v acc = {0.f,0.f,0.f,0.f};
    const ushort_t* arow = wtf + ((size_t)(grp*KS)*64 + lane)*8;
    const ushort_t* brow = s_s + n*SROW + quad*8;
    half8 a_cur = *(const half8*)(arow);
#pragma unroll
    for (int ks = 0; ks < KS; ++ks) {
        half8 a_next = a_cur;
        if (ks < KS-1) a_next = *(const half8*)(arow + (ks+1)*512);
        half8 bf = *(const half8*)(brow + ks*32);
        acc = MFMA16(a_cur, bf, acc);
        a_cur = a_next;
    }

#pragma unroll
    for (int r = 0; r < 4; ++r) {
        int o = grp*16 + quad*4 + r;
        out[(((size_t)b*OUTq + o)*Hq + i)*Wq + j0 + n] = acc[r];
    }
}

// ---------------------------------------------------------------------------
extern "C" void kernel_launch(void* const* d_in, const int* in_sizes, int n_in,
                              void* d_out, int out_size, void* d_ws, size_t ws_size,
                              hipStream_t stream) {
    const float* x     = (const float*)d_in[0];
    const float* off_w = (const float*)d_in[1];
    const float* off_b = (const float*)d_in[2];
    const float* msk_w = (const float*)d_in[3];
    const float* msk_b = (const float*)d_in[4];
    const float* dcn_w = (const float*)d_in[5];
    float* out = (float*)d_out;

    char* ws = (char*)d_ws;
    ushort_t* xt   = (ushort_t*)ws;                  // 13,107,200 B
    ushort_t* wtf  = xt + (size_t)Bq*HWq*64;         //     73,728 B
    ushort_t* cwf2 = wtf + 4*KS*512;                 //     36,864 B

    hipLaunchKernelGGL(k_prep, dim3(HWq/64, Bq), dim3(256), 0, stream,
                       x, dcn_w, off_w, msk_w, xt, wtf, cwf2);
    hipLaunchKernelGGL(k_fused, dim3(Bq*Hq*10), dim3(256), 0, stream,
                       xt, cwf2, off_b, msk_b, wtf, out);
}

// Round 10
// 130.184 us; speedup vs baseline: 1.2273x; 1.2273x over previous
//
#include <hip/hip_runtime.h>
#include <math.h>

#define Bq 4
#define Cq 64
#define Hq 160
#define Wq 160
#define HWq (Hq*Wq)      // 25600
#define OUTq 64
#define KKq 576          // Cq*9
#define KS  18           // KKq/32
#define SROW 584         // padded kk row (fp16 units); 1168 B, rows 16B-aligned
#define HSTRIDE 72       // halo px stride (ushorts) = 144 B

typedef __attribute__((ext_vector_type(8))) _Float16 half8;
typedef __attribute__((ext_vector_type(2))) _Float16 half2v;
typedef __attribute__((ext_vector_type(4))) float float4v;
typedef __attribute__((ext_vector_type(4))) unsigned short ushort4v;
typedef unsigned short ushort_t;
typedef unsigned int uint_t;

__device__ __forceinline__ ushort_t f2h(float f) {          // RNE f32->f16
    return __builtin_bit_cast(ushort_t, (_Float16)f);
}
__device__ __forceinline__ uint_t f2hdup(float f) {         // (h,h) packed
    uint_t u = (uint_t)f2h(f);
    return u | (u << 16);
}
__device__ __forceinline__ half2v h2(uint_t u) {
    return __builtin_bit_cast(half2v, u);
}
#define MFMA16(a,b,c) __builtin_amdgcn_mfma_f32_16x16x32_f16((a),(b),(c),0,0,0)

// ---------------------------------------------------------------------------
// K_prep: x NCHW f32 -> xt NHWC fp16; weight prepack on first 216 blocks.
//  Vectorized: float4 global loads, uint2 (4-ch) packed stores.
//  tile[64][65]: stride-65 floats => all LDS accesses <=2-way (free).
// ---------------------------------------------------------------------------
__global__ void __launch_bounds__(256) k_prep(const float* __restrict__ x,
                                              const float* __restrict__ dcn_w,
                                              const float* __restrict__ off_w,
                                              const float* __restrict__ msk_w,
                                              ushort_t* __restrict__ xt,
                                              ushort_t* __restrict__ wtf,
                                              ushort_t* __restrict__ cwf2) {
    __shared__ float tile[64][65];
    int b = blockIdx.y, hw0 = blockIdx.x * 64;
    int tid = threadIdx.x;
    int l16 = tid & 15, crow = tid >> 4;        // crow 0..15
#pragma unroll
    for (int i = 0; i < 4; ++i) {
        int c = crow + i*16;
        float4 v = *(const float4*)(x + ((size_t)(b*Cq + c))*HWq + hw0 + l16*4);
        tile[c][l16*4+0] = v.x;
        tile[c][l16*4+1] = v.y;
        tile[c][l16*4+2] = v.z;
        tile[c][l16*4+3] = v.w;
    }
    __syncthreads();
#pragma unroll
    for (int it = 0; it < 4; ++it) {
        int hw = (tid >> 4) + it*16;
        int c4 = (tid & 15) * 4;
        uint_t v0 = (uint_t)f2h(tile[c4+0][hw]) | ((uint_t)f2h(tile[c4+1][hw]) << 16);
        uint_t v1 = (uint_t)f2h(tile[c4+2][hw]) | ((uint_t)f2h(tile[c4+3][hw]) << 16);
        uint2 vv; vv.x = v0; vv.y = v1;
        *(uint2*)(xt + ((size_t)b*HWq + hw0 + hw)*64 + c4) = vv;
    }
    if (blockIdx.y == 0 && blockIdx.x < 216) {
        int id = blockIdx.x*256 + tid;
        if (id < 4*KS*512) {
            int j = id & 7, ln = (id>>3) & 63, ks = (id>>9) % KS, g = id/(512*KS);
            int kk = ks*32 + (ln>>4)*8 + j;
            int c  = kk & 63, kt = kk >> 6;
            int m  = g*16 + (ln&15);
            wtf[id] = f2h(dcn_w[m*KKq + c*9 + kt]);
        }
        int id2 = id - 4*KS*512;
        if (id2 >= 0 && id2 < 9*2*2*512) {
            int j = id2 & 7, ln = (id2>>3) & 63;
            int ks2 = (id2>>9) & 1, g = (id2>>10) & 1, k = id2 >> 11;
            int co = g*16 + (ln&15);
            int c  = ks2*32 + (ln>>4)*8 + j;
            float w = 0.f;
            if (co < 18)      w = off_w[co*KKq + c*9 + k];
            else if (co < 27) w = msk_w[(co-18)*KKq + c*9 + k];
            cwf2[id2] = f2h(w);
        }
    }
}

// ---------------------------------------------------------------------------
// K_fused = r6 (measured best, 50.2us) + s_setprio around MFMA clusters.
//  r6 structure: XCD swizzle (800-block chunk per XCD), conv a-frags hoisted
//  above halo barrier, halo staging 3x18, half-wave Phase B (2 ch/lane,
//  dword gathers, 1-deep pipeline), u16 pixel-index descriptors (<<7 at
//  use), pre-duplicated fp16 premasked weights, Phase C 1-deep a-prefetch.
//  setprio: blocks on a CU run phase-skewed (no inter-block sync), so
//  boosting waves inside their MFMA clusters wins issue arbitration over
//  co-resident waves doing staging/gathers (T5 regime).
// LDS: union{halo(7776)+partials(4096) | s_s(18688)} + s_A16(1152) + s_W(2304)
//    = 22144 B.
// ---------------------------------------------------------------------------
__global__ void __launch_bounds__(256, 6) k_fused(const ushort_t* __restrict__ xt,
                                                  const ushort_t* __restrict__ cwf2,
                                                  const float* __restrict__ off_b,
                                                  const float* __restrict__ msk_b,
                                                  const ushort_t* __restrict__ wtf,
                                                  float* __restrict__ out) {
    __shared__ __align__(16) char s_mem[16*SROW*2];          // 18,688 B
    __shared__ __align__(16) ushort4v s_A16[144];            //  1,152 B
    __shared__ __align__(16) uint4 s_W[144];                 //  2,304 B
    ushort_t* halo   = (ushort_t*)s_mem;                     // [0, 7776)
    float*    s_part = (float*)(s_mem + 7776);               // [7776, 11872)
    ushort_t* s_s    = (ushort_t*)s_mem;                     // Phase B/C

    // XCD-aware swizzle: contiguous 800-block chunk per XCD.
    int bid = blockIdx.x;                 // 6400 = 4 * 160 * 10
    int blk = (bid & 7) * 800 + (bid >> 3);
    int jt = blk % 10, i = (blk/10) % Hq, b = blk/(10*Hq);
    int j0 = jt*16;
    int tid = threadIdx.x, lane = tid & 63, grp = tid >> 6;
    int n = lane & 15, quad = lane >> 4;

    // ---- Conv A-fragments: hoisted loads (independent of halo) ----
    int gM = grp & 1, kh = grp >> 1;
    half8 af[9];
#pragma unroll
    for (int s = 0; s < 9; ++s) {
        int st = kh*9 + s;                // 0..17
        int k = st >> 1, ks2 = st & 1;
        af[s] = *(const half8*)(cwf2 + (size_t)(((k*2+gM)*2+ks2)*512 + lane*8));
    }

    // ---- Stage halo: 3 rows x 18 px x 64 ch fp16 ----
    const ushort_t* xtb = xt + (size_t)b*HWq*64;
#pragma unroll
    for (int t = tid; t < 432; t += 256) {
        int seg = t >> 3, sub = t & 7;
        int ky = seg / 18, px = seg % 18;
        int y = i + ky - 1, xx = j0 + px - 1;
        uint4 v = {0u,0u,0u,0u};
        if (y >= 0 && y < Hq && xx >= 0 && xx < Wq)
            v = *(const uint4*)(xtb + ((size_t)y*Wq + xx)*64 + sub*8);
        *(uint4*)(halo + (ky*18 + px)*HSTRIDE + sub*8) = v;
    }
    __syncthreads();

    // ---- Offset/mask conv: wave (gM, kh) over 9 K-steps each ----
    {
        float4v cacc = {0.f,0.f,0.f,0.f};
        __builtin_amdgcn_s_setprio(1);
#pragma unroll
        for (int s = 0; s < 9; ++s) {
            int st = kh*9 + s;            // 0..17
            int k = st >> 1, ks2 = st & 1;
            int ky = k/3, kx = k - (k/3)*3;
            half8 bf = *(const half8*)(halo + (ky*18 + n + kx)*HSTRIDE + quad*8 + ks2*32);
            cacc = MFMA16(af[s], bf, cacc);
        }
        __builtin_amdgcn_s_setprio(0);
        *(float4v*)(s_part + grp*256 + lane*4) = cacc;
    }
    __syncthreads();

    // ---- Phase A: tap descriptors from conv partials ----
    if (tid < 144) {
        int p = tid & 15, k = tid >> 4;
        #define RD(co) (s_part[(((co)>>4)*256)     + ((((co)&15)>>2)*16 + p)*4 + ((co)&3)] + \
                        s_part[(2 + ((co)>>4))*256 + ((((co)&15)>>2)*16 + p)*4 + ((co)&3)])
        float oy = RD(2*k)   + off_b[2*k];
        float ox = RD(2*k+1) + off_b[2*k+1];
        float mv = RD(18+k)  + msk_b[k];
        #undef RD
        float m = 1.f/(1.f + __expf(-mv));
        float py = oy + (float)(i - 1 + k/3);
        float px = ox + (float)(j0 + p - 1 + (k - (k/3)*3));
        float fy = floorf(py), fx = floorf(px);
        int y0 = (int)fy, x0 = (int)fx;
        float wy1 = py - fy, wx1 = px - fx;
        float wy0 = 1.f - wy1, wx0 = 1.f - wx1;
        bool vy0 = (y0 >= 0) & (y0 < Hq),   vy1 = (y0+1 >= 0) & (y0+1 < Hq);
        bool vx0 = (x0 >= 0) & (x0 < Wq),   vx1 = (x0+1 >= 0) & (x0+1 < Wq);
        int yc0 = min(max(y0,   0), Hq-1), yc1 = min(max(y0+1, 0), Hq-1);
        int xc0 = min(max(x0,   0), Wq-1), xc1 = min(max(x0+1, 0), Wq-1);
        ushort4v av;
        av.x = (ushort_t)(yc0*Wq + xc0);
        av.y = (ushort_t)(yc0*Wq + xc1);
        av.z = (ushort_t)(yc1*Wq + xc0);
        av.w = (ushort_t)(yc1*Wq + xc1);
        s_A16[tid] = av;
        s_W[tid] = make_uint4(f2hdup((vy0 && vx0) ? wy0*wx0*m : 0.f),
                              f2hdup((vy0 && vx1) ? wy0*wx1*m : 0.f),
                              f2hdup((vy1 && vx0) ? wy1*wx0*m : 0.f),
                              f2hdup((vy1 && vx1) ? wy1*wx1*m : 0.f));
    }
    __syncthreads();

    // ---- Phase B: half-wave per (p,tap), 2 ch/lane, 1-deep pipelined ----
    {
        int lane4 = (lane & 31) * 4;
        int halfi = lane >> 5;
        const char* xtbB = (const char*)xtb;
        char* s_sb = (char*)s_s;
        int t2h = grp*2 + halfi;                 // task for iter 0
        ushort4v A = s_A16[t2h];
        uint4 Wt   = s_W[t2h];
        uint_t u00 = *(const uint_t*)(xtbB + (((uint_t)A.x) << 7) + lane4);
        uint_t u01 = *(const uint_t*)(xtbB + (((uint_t)A.y) << 7) + lane4);
        uint_t u10 = *(const uint_t*)(xtbB + (((uint_t)A.z) << 7) + lane4);
        uint_t u11 = *(const uint_t*)(xtbB + (((uint_t)A.w) << 7) + lane4);
#pragma unroll
        for (int iter = 0; iter < 18; ++iter) {
            int t_cur = t2h;
            uint4 Wc = Wt;
            uint_t v00 = u00, v01 = u01, v10 = u10, v11 = u11;
            if (iter < 17) {                     // prefetch iter+1
                t2h += 8;
                A  = s_A16[t2h];
                Wt = s_W[t2h];
                u00 = *(const uint_t*)(xtbB + (((uint_t)A.x) << 7) + lane4);
                u01 = *(const uint_t*)(xtbB + (((uint_t)A.y) << 7) + lane4);
                u10 = *(const uint_t*)(xtbB + (((uint_t)A.z) << 7) + lane4);
                u11 = *(const uint_t*)(xtbB + (((uint_t)A.w) << 7) + lane4);
            }
            uint_t dst = (uint_t)((t_cur & 15)*(SROW*2) + (t_cur >> 4)*128);
            half2v acc2 = h2(v00) * h2(Wc.x);
            acc2 = __builtin_elementwise_fma(h2(v01), h2(Wc.y), acc2);
            acc2 = __builtin_elementwise_fma(h2(v10), h2(Wc.z), acc2);
            acc2 = __builtin_elementwise_fma(h2(v11), h2(Wc.w), acc2);
            *(uint_t*)(s_sb + dst + lane4) = __builtin_bit_cast(uint_t, acc2);
        }
    }
    __syncthreads();

    // ---- Phase C: wave grp -> o rows [grp*16, +16), 16 pixels ----
    float4v acc = {0.f,0.f,0.f,0.f};
    const ushort_t* arow = wtf + ((size_t)(grp*KS)*64 + lane)*8;
    const ushort_t* brow = s_s + n*SROW + quad*8;
    half8 a_cur = *(const half8*)(arow);
    __builtin_amdgcn_s_setprio(1);
#pragma unroll
    for (int ks = 0; ks < KS; ++ks) {
        half8 a_next = a_cur;
        if (ks < KS-1) a_next = *(const half8*)(arow + (ks+1)*512);
        half8 bf = *(const half8*)(brow + ks*32);
        acc = MFMA16(a_cur, bf, acc);
        a_cur = a_next;
    }
    __builtin_amdgcn_s_setprio(0);

#pragma unroll
    for (int r = 0; r < 4; ++r) {
        int o = grp*16 + quad*4 + r;
        out[(((size_t)b*OUTq + o)*Hq + i)*Wq + j0 + n] = acc[r];
    }
}

// ---------------------------------------------------------------------------
extern "C" void kernel_launch(void* const* d_in, const int* in_sizes, int n_in,
                              void* d_out, int out_size, void* d_ws, size_t ws_size,
                              hipStream_t stream) {
    const float* x     = (const float*)d_in[0];
    const float* off_w = (const float*)d_in[1];
    const float* off_b = (const float*)d_in[2];
    const float* msk_w = (const float*)d_in[3];
    const float* msk_b = (const float*)d_in[4];
    const float* dcn_w = (const float*)d_in[5];
    float* out = (float*)d_out;

    char* ws = (char*)d_ws;
    ushort_t* xt   = (ushort_t*)ws;                  // 13,107,200 B
    ushort_t* wtf  = xt + (size_t)Bq*HWq*64;         //     73,728 B
    ushort_t* cwf2 = wtf + 4*KS*512;                 //     36,864 B

    hipLaunchKernelGGL(k_prep, dim3(HWq/64, Bq), dim3(256), 0, stream,
                       x, dcn_w, off_w, msk_w, xt, wtf, cwf2);
    hipLaunchKernelGGL(k_fused, dim3(Bq*Hq*10), dim3(256), 0, stream,
                       xt, cwf2, off_b, msk_b, wtf, out);
}

// Round 11
// 127.583 us; speedup vs baseline: 1.2523x; 1.0204x over previous
//
#include <hip/hip_runtime.h>
#include <math.h>

#define Bq 4
#define Cq 64
#define Hq 160
#define Wq 160
#define HWq (Hq*Wq)      // 25600
#define OUTq 64
#define KKq 576          // Cq*9
#define KS  18           // KKq/32
#define SROW 584         // padded kk row (fp16 units); 1168 B, rows 16B-aligned
#define HSTRIDE 72       // halo px stride (ushorts) = 144 B

typedef __attribute__((ext_vector_type(8))) _Float16 half8;
typedef __attribute__((ext_vector_type(2))) _Float16 half2v;
typedef __attribute__((ext_vector_type(4))) float float4v;
typedef __attribute__((ext_vector_type(4))) unsigned short ushort4v;
typedef unsigned short ushort_t;
typedef unsigned int uint_t;

__device__ __forceinline__ ushort_t f2h(float f) {          // RNE f32->f16
    return __builtin_bit_cast(ushort_t, (_Float16)f);
}
__device__ __forceinline__ uint_t f2hdup(float f) {         // (h,h) packed
    uint_t u = (uint_t)f2h(f);
    return u | (u << 16);
}
__device__ __forceinline__ half2v h2(uint_t u) {
    return __builtin_bit_cast(half2v, u);
}
#define MFMA16(a,b,c) __builtin_amdgcn_mfma_f32_16x16x32_f16((a),(b),(c),0,0,0)

// ---------------------------------------------------------------------------
// K_prep: x NCHW f32 -> xt NHWC fp16; weight prepack on first 216 blocks.
//  Vectorized: float4 global loads, uint2 (4-ch) packed stores.
//  tile[64][65]: stride-65 floats => all LDS accesses <=2-way (free).
// ---------------------------------------------------------------------------
__global__ void __launch_bounds__(256) k_prep(const float* __restrict__ x,
                                              const float* __restrict__ dcn_w,
                                              const float* __restrict__ off_w,
                                              const float* __restrict__ msk_w,
                                              ushort_t* __restrict__ xt,
                                              ushort_t* __restrict__ wtf,
                                              ushort_t* __restrict__ cwf2) {
    __shared__ float tile[64][65];
    int b = blockIdx.y, hw0 = blockIdx.x * 64;
    int tid = threadIdx.x;
    int l16 = tid & 15, crow = tid >> 4;        // crow 0..15
#pragma unroll
    for (int i = 0; i < 4; ++i) {
        int c = crow + i*16;
        float4 v = *(const float4*)(x + ((size_t)(b*Cq + c))*HWq + hw0 + l16*4);
        tile[c][l16*4+0] = v.x;
        tile[c][l16*4+1] = v.y;
        tile[c][l16*4+2] = v.z;
        tile[c][l16*4+3] = v.w;
    }
    __syncthreads();
#pragma unroll
    for (int it = 0; it < 4; ++it) {
        int hw = (tid >> 4) + it*16;
        int c4 = (tid & 15) * 4;
        uint_t v0 = (uint_t)f2h(tile[c4+0][hw]) | ((uint_t)f2h(tile[c4+1][hw]) << 16);
        uint_t v1 = (uint_t)f2h(tile[c4+2][hw]) | ((uint_t)f2h(tile[c4+3][hw]) << 16);
        uint2 vv; vv.x = v0; vv.y = v1;
        *(uint2*)(xt + ((size_t)b*HWq + hw0 + hw)*64 + c4) = vv;
    }
    if (blockIdx.y == 0 && blockIdx.x < 216) {
        int id = blockIdx.x*256 + tid;
        if (id < 4*KS*512) {
            int j = id & 7, ln = (id>>3) & 63, ks = (id>>9) % KS, g = id/(512*KS);
            int kk = ks*32 + (ln>>4)*8 + j;
            int c  = kk & 63, kt = kk >> 6;
            int m  = g*16 + (ln&15);
            wtf[id] = f2h(dcn_w[m*KKq + c*9 + kt]);
        }
        int id2 = id - 4*KS*512;
        if (id2 >= 0 && id2 < 9*2*2*512) {
            int j = id2 & 7, ln = (id2>>3) & 63;
            int ks2 = (id2>>9) & 1, g = (id2>>10) & 1, k = id2 >> 11;
            int co = g*16 + (ln&15);
            int c  = ks2*32 + (ln>>4)*8 + j;
            float w = 0.f;
            if (co < 18)      w = off_w[co*KKq + c*9 + k];
            else if (co < 27) w = msk_w[(co-18)*KKq + c*9 + k];
            cwf2[id2] = f2h(w);
        }
    }
}

// ---------------------------------------------------------------------------
// K_fused = r6, the measured best (50.2 us):
//  - XCD-aware swizzle: contiguous 800-block chunk per XCD -> xt working set
//    1.6 MB fits per-XCD L2 (FETCH 30.5 -> 7.0 MB measured)
//  - conv a-frags hoisted above the halo barrier (L2 latency hidden)
//  - halo staging 3x18 px in LDS (load-bearing: de-halo'd conv regressed 38%)
//  - Phase B: half-wave per (p,tap), 2 ch/lane, dword gathers, 1-deep
//    software pipeline (deeper refused by RA / null)
//  - u16 pixel-index descriptors (<<7 at use), pre-duplicated premasked
//    fp16 corner weights
//  - Phase C 1-deep a-row prefetch
//  NOT included (measured null or regressive): setprio (r10), quarter-wave
//  gathers (r1/r9), LDS gathers (r4), 2-row blocks (r7), depth-3 (r8).
// LDS: union{halo(7776)+partials(4096) | s_s(18688)} + s_A16(1152) + s_W(2304)
//    = 22144 B.
// ---------------------------------------------------------------------------
__global__ void __launch_bounds__(256, 6) k_fused(const ushort_t* __restrict__ xt,
                                                  const ushort_t* __restrict__ cwf2,
                                                  const float* __restrict__ off_b,
                                                  const float* __restrict__ msk_b,
                                                  const ushort_t* __restrict__ wtf,
                                                  float* __restrict__ out) {
    __shared__ __align__(16) char s_mem[16*SROW*2];          // 18,688 B
    __shared__ __align__(16) ushort4v s_A16[144];            //  1,152 B
    __shared__ __align__(16) uint4 s_W[144];                 //  2,304 B
    ushort_t* halo   = (ushort_t*)s_mem;                     // [0, 7776)
    float*    s_part = (float*)(s_mem + 7776);               // [7776, 11872)
    ushort_t* s_s    = (ushort_t*)s_mem;                     // Phase B/C

    // XCD-aware swizzle: contiguous 800-block chunk per XCD.
    int bid = blockIdx.x;                 // 6400 = 4 * 160 * 10
    int blk = (bid & 7) * 800 + (bid >> 3);
    int jt = blk % 10, i = (blk/10) % Hq, b = blk/(10*Hq);
    int j0 = jt*16;
    int tid = threadIdx.x, lane = tid & 63, grp = tid >> 6;
    int n = lane & 15, quad = lane >> 4;

    // ---- Conv A-fragments: hoisted loads (independent of halo) ----
    int gM = grp & 1, kh = grp >> 1;
    half8 af[9];
#pragma unroll
    for (int s = 0; s < 9; ++s) {
        int st = kh*9 + s;                // 0..17
        int k = st >> 1, ks2 = st & 1;
        af[s] = *(const half8*)(cwf2 + (size_t)(((k*2+gM)*2+ks2)*512 + lane*8));
    }

    // ---- Stage halo: 3 rows x 18 px x 64 ch fp16 ----
    const ushort_t* xtb = xt + (size_t)b*HWq*64;
#pragma unroll
    for (int t = tid; t < 432; t += 256) {
        int seg = t >> 3, sub = t & 7;
        int ky = seg / 18, px = seg % 18;
        int y = i + ky - 1, xx = j0 + px - 1;
        uint4 v = {0u,0u,0u,0u};
        if (y >= 0 && y < Hq && xx >= 0 && xx < Wq)
            v = *(const uint4*)(xtb + ((size_t)y*Wq + xx)*64 + sub*8);
        *(uint4*)(halo + (ky*18 + px)*HSTRIDE + sub*8) = v;
    }
    __syncthreads();

    // ---- Offset/mask conv: wave (gM, kh) over 9 K-steps each ----
    {
        float4v cacc = {0.f,0.f,0.f,0.f};
#pragma unroll
        for (int s = 0; s < 9; ++s) {
            int st = kh*9 + s;            // 0..17
            int k = st >> 1, ks2 = st & 1;
            int ky = k/3, kx = k - (k/3)*3;
            half8 bf = *(const half8*)(halo + (ky*18 + n + kx)*HSTRIDE + quad*8 + ks2*32);
            cacc = MFMA16(af[s], bf, cacc);
        }
        *(float4v*)(s_part + grp*256 + lane*4) = cacc;
    }
    __syncthreads();

    // ---- Phase A: tap descriptors from conv partials ----
    if (tid < 144) {
        int p = tid & 15, k = tid >> 4;
        #define RD(co) (s_part[(((co)>>4)*256)     + ((((co)&15)>>2)*16 + p)*4 + ((co)&3)] + \
                        s_part[(2 + ((co)>>4))*256 + ((((co)&15)>>2)*16 + p)*4 + ((co)&3)])
        float oy = RD(2*k)   + off_b[2*k];
        float ox = RD(2*k+1) + off_b[2*k+1];
        float mv = RD(18+k)  + msk_b[k];
        #undef RD
        float m = 1.f/(1.f + __expf(-mv));
        float py = oy + (float)(i - 1 + k/3);
        float px = ox + (float)(j0 + p - 1 + (k - (k/3)*3));
        float fy = floorf(py), fx = floorf(px);
        int y0 = (int)fy, x0 = (int)fx;
        float wy1 = py - fy, wx1 = px - fx;
        float wy0 = 1.f - wy1, wx0 = 1.f - wx1;
        bool vy0 = (y0 >= 0) & (y0 < Hq),   vy1 = (y0+1 >= 0) & (y0+1 < Hq);
        bool vx0 = (x0 >= 0) & (x0 < Wq),   vx1 = (x0+1 >= 0) & (x0+1 < Wq);
        int yc0 = min(max(y0,   0), Hq-1), yc1 = min(max(y0+1, 0), Hq-1);
        int xc0 = min(max(x0,   0), Wq-1), xc1 = min(max(x0+1, 0), Wq-1);
        ushort4v av;
        av.x = (ushort_t)(yc0*Wq + xc0);
        av.y = (ushort_t)(yc0*Wq + xc1);
        av.z = (ushort_t)(yc1*Wq + xc0);
        av.w = (ushort_t)(yc1*Wq + xc1);
        s_A16[tid] = av;
        s_W[tid] = make_uint4(f2hdup((vy0 && vx0) ? wy0*wx0*m : 0.f),
                              f2hdup((vy0 && vx1) ? wy0*wx1*m : 0.f),
                              f2hdup((vy1 && vx0) ? wy1*wx0*m : 0.f),
                              f2hdup((vy1 && vx1) ? wy1*wx1*m : 0.f));
    }
    __syncthreads();

    // ---- Phase B: half-wave per (p,tap), 2 ch/lane, 1-deep pipelined ----
    {
        int lane4 = (lane & 31) * 4;
        int halfi = lane >> 5;
        const char* xtbB = (const char*)xtb;
        char* s_sb = (char*)s_s;
        int t2h = grp*2 + halfi;                 // task for iter 0
        ushort4v A = s_A16[t2h];
        uint4 Wt   = s_W[t2h];
        uint_t u00 = *(const uint_t*)(xtbB + (((uint_t)A.x) << 7) + lane4);
        uint_t u01 = *(const uint_t*)(xtbB + (((uint_t)A.y) << 7) + lane4);
        uint_t u10 = *(const uint_t*)(xtbB + (((uint_t)A.z) << 7) + lane4);
        uint_t u11 = *(const uint_t*)(xtbB + (((uint_t)A.w) << 7) + lane4);
#pragma unroll
        for (int iter = 0; iter < 18; ++iter) {
            int t_cur = t2h;
            uint4 Wc = Wt;
            uint_t v00 = u00, v01 = u01, v10 = u10, v11 = u11;
            if (iter < 17) {                     // prefetch iter+1
                t2h += 8;
                A  = s_A16[t2h];
                Wt = s_W[t2h];
                u00 = *(const uint_t*)(xtbB + (((uint_t)A.x) << 7) + lane4);
                u01 = *(const uint_t*)(xtbB + (((uint_t)A.y) << 7) + lane4);
                u10 = *(const uint_t*)(xtbB + (((uint_t)A.z) << 7) + lane4);
                u11 = *(const uint_t*)(xtbB + (((uint_t)A.w) << 7) + lane4);
            }
            uint_t dst = (uint_t)((t_cur & 15)*(SROW*2) + (t_cur >> 4)*128);
            half2v acc2 = h2(v00) * h2(Wc.x);
            acc2 = __builtin_elementwise_fma(h2(v01), h2(Wc.y), acc2);
            acc2 = __builtin_elementwise_fma(h2(v10), h2(Wc.z), acc2);
            acc2 = __builtin_elementwise_fma(h2(v11), h2(Wc.w), acc2);
            *(uint_t*)(s_sb + dst + lane4) = __builtin_bit_cast(uint_t, acc2);
        }
    }
    __syncthreads();

    // ---- Phase C: wave grp -> o rows [grp*16, +16), 16 pixels ----
    float4v acc = {0.f,0.f,0.f,0.f};
    const ushort_t* arow = wtf + ((size_t)(grp*KS)*64 + lane)*8;
    const ushort_t* brow = s_s + n*SROW + quad*8;
    half8 a_cur = *(const half8*)(arow);
#pragma unroll
    for (int ks = 0; ks < KS; ++ks) {
        half8 a_next = a_cur;
        if (ks < KS-1) a_next = *(const half8*)(arow + (ks+1)*512);
        half8 bf = *(const half8*)(brow + ks*32);
        acc = MFMA16(a_cur, bf, acc);
        a_cur = a_next;
    }

#pragma unroll
    for (int r = 0; r < 4; ++r) {
        int o = grp*16 + quad*4 + r;
        out[(((size_t)b*OUTq + o)*Hq + i)*Wq + j0 + n] = acc[r];
    }
}

// ---------------------------------------------------------------------------
extern "C" void kernel_launch(void* const* d_in, const int* in_sizes, int n_in,
                              void* d_out, int out_size, void* d_ws, size_t ws_size,
                              hipStream_t stream) {
    const float* x     = (const float*)d_in[0];
    const float* off_w = (const float*)d_in[1];
    const float* off_b = (const float*)d_in[2];
    const float* msk_w = (const float*)d_in[3];
    const float* msk_b = (const float*)d_in[4];
    const float* dcn_w = (const float*)d_in[5];
    float* out = (float*)d_out;

    char* ws = (char*)d_ws;
    ushort_t* xt   = (ushort_t*)ws;                  // 13,107,200 B
    ushort_t* wtf  = xt + (size_t)Bq*HWq*64;         //     73,728 B
    ushort_t* cwf2 = wtf + 4*KS*512;                 //     36,864 B

    hipLaunchKernelGGL(k_prep, dim3(HWq/64, Bq), dim3(256), 0, stream,
                       x, dcn_w, off_w, msk_w, xt, wtf, cwf2);
    hipLaunchKernelGGL(k_fused, dim3(Bq*Hq*10), dim3(256), 0, stream,
                       xt, cwf2, off_b, msk_b, wtf, out);
}